// Round 5
// baseline (195.623 us; speedup 1.0000x reference)
//
#include <hip/hip_runtime.h>
#include <hip/hip_cooperative_groups.h>

// GAT spatio-temporal model — cooperative mega-kernel with occupancy-gated
// fallback to the proven multi-kernel pipeline. bf16 MFMA throughout.
// B=8, N=512, Din=64, H=8, F=128, L=2.

namespace cg = cooperative_groups;

constexpr int B = 8, N = 512, DIN = 64, H = 8, F = 128;
constexpr int BN = B * N;          // 4096
constexpr float ALPHA_LR = 0.2f;   // LeakyReLU slope
constexpr float EPS_LN = 1e-5f;
constexpr float FLOW = -3.0e38f;   // "-inf" substitute

typedef __attribute__((ext_vector_type(8))) short short8;  // 8 bf16
typedef __attribute__((ext_vector_type(4))) float f32x4;

__device__ __forceinline__ f32x4 mfma16(short8 a, short8 b, f32x4 c) {
  return __builtin_amdgcn_mfma_f32_16x16x32_bf16(a, b, c, 0, 0, 0);
}

__device__ __forceinline__ short f2bf(float f) {  // RNE f32 -> bf16 bits
  union { float f; unsigned u; } v;
  v.f = f;
  unsigned r = v.u + 0x7FFFu + ((v.u >> 16) & 1u);
  return (short)(r >> 16);
}

struct KParams {
  const float* x; const int* adj; const float* Wp; const float* bp;
  const float* W_heads; const float* a_heads; const float* W_out;
  const float* a_out; const float* ln_g; const float* ln_b;
  float* h; short* hb; unsigned long long* amask; short* WTh; short* WoT;
  short* hhT; short* multi; short* hsT; float* sA; float* dout;
};

// ---- shared-memory stage overlays ----
struct SM_PH { short As[64 * 136]; short Bs[128 * 136]; };          // 52224 B
struct SM_AH {                                                      // 55040 B
  short Vs[128 * 136]; short Pf[16 * 64 * 8]; float s2all[512];
  float s1r[64]; float mrow[64]; float linv[64]; float red[64][4];
};
struct SM_PO { short As[32 * 136]; short Bs[32 * 136]; };           // 17408 B
struct SM_AS {                                                      // 51776 B
  short Vs[128 * 136]; short Pf[4 * 64 * 8]; float s2all[512];
  float Ot[16][132]; float redS[16][16]; float redQ[16][16];
  float s1r[16]; float mrow[16]; float linv[16]; float muA[16]; float rsA[16];
};
struct SM_SU { float T[32][33]; float xr[2][64]; };

// ================= stage 0: zero sA | adjmask | proj_in | transposes ======
// expects grid == 512 blocks x 256 threads
__device__ __forceinline__ void st_setup(const KParams& P, int bid, int tid,
                                         char* smraw) {
  for (int i = tid; i < 288; i += 256) P.sA[(size_t)bid * 288 + i] = 0.f;
  {  // adjacency -> 64-bit masks (16 words/wave; loads batched in-flight)
    int lane = tid & 63, wv = tid >> 6;
    int v[16];
#pragma unroll
    for (int j = 0; j < 16; j++) {
      int w = (bid + j * 512) * 4 + wv;
      v[j] = P.adj[(size_t)w * 64 + lane];
    }
#pragma unroll
    for (int j = 0; j < 16; j++) {
      int w = (bid + j * 512) * 4 + wv;
      unsigned long long m = __ballot(v[j] > 0);
      if (lane == 0) P.amask[w] = m;
    }
  }
  {  // input projection: h = relu(x@Wp+bp) (+bf16 copy), 2 rows per unit
    SM_SU* s = (SM_SU*)smraw;
    int half = tid >> 7, f = tid & 127;
    for (int u = bid; u < 2048; u += 512) {
      int row = u * 2 + half;
      __syncthreads();
      if (f < 64) s->xr[half][f] = P.x[(size_t)row * DIN + f];
      __syncthreads();
      float acc = P.bp[f];
#pragma unroll
      for (int i = 0; i < DIN; i++)
        acc = fmaf(s->xr[half][i], P.Wp[i * F + f], acc);
      acc = fmaxf(acc, 0.f);
      P.h[(size_t)row * F + f] = acc;
      P.hb[(size_t)row * F + f] = f2bf(acc);
    }
  }
  {  // weight transposes f32 [bt][R][C] -> bf16 [bt][C][R], one 32x32 tile
    SM_SU* s = (SM_SU*)smraw;
    const float* in; short* out; int R, C, bx, by, bt;
    if (bid < 256) {
      in = P.W_heads; out = P.WTh; R = 128; C = 128;
      bx = bid & 3; by = (bid >> 2) & 3; bt = bid >> 4;
    } else {
      int i = bid - 256;
      in = P.W_out; out = P.WoT; R = 1024; C = 128;
      bx = i & 3; by = (i >> 2) & 31; bt = i >> 7;
    }
    int c0 = bx * 32, r0 = by * 32;
    const float* ip = in + (size_t)bt * R * C;
    short* op = out + (size_t)bt * R * C;
    __syncthreads();
    {
      int r = tid >> 3, c4 = (tid & 7) * 4;
      float4 v = *(const float4*)(ip + (size_t)(r0 + r) * C + c0 + c4);
      s->T[r][c4] = v.x; s->T[r][c4 + 1] = v.y;
      s->T[r][c4 + 2] = v.z; s->T[r][c4 + 3] = v.w;
    }
    __syncthreads();
    {
      int cr = tid >> 3, q = (tid & 7) * 4;
      short4 o;
      o.x = f2bf(s->T[q][cr]); o.y = f2bf(s->T[q + 1][cr]);
      o.z = f2bf(s->T[q + 2][cr]); o.w = f2bf(s->T[q + 3][cr]);
      *(short4*)(op + (size_t)(c0 + cr) * R + r0 + q) = o;
    }
  }
}

// ====== head projection: hhT[bh][f_out][n] = WT[h].hb^T, + s1/s2 epilogue ==
// 512 units: nt(4) x ft(2) x bh(64)
__device__ __forceinline__ void st_proj_heads(
    const KParams& P, const short* WT, const float* ah_base, float* s1,
    float* s2, int bid, int tid, char* smraw) {
  SM_PH* sm = (SM_PH*)smraw;
  int nt = bid & 3, ft = (bid >> 2) & 1, bh = bid >> 3;
  int b = bh >> 3, hd = bh & 7;
  int n0 = nt * 128;
  constexpr int LK = 136;
  int lane = tid & 63, w = tid >> 6;
  {
    int r = tid >> 2, q = tid & 3;
    const uint4* g = (const uint4*)(WT + ((size_t)hd * F + ft * 64 + r) * F) + q * 4;
    uint4* lp = (uint4*)(sm->As + r * LK) + q * 4;
    lp[0] = g[0]; lp[1] = g[1]; lp[2] = g[2]; lp[3] = g[3];
  }
  {
    int q = tid & 3;
    for (int r = tid >> 2; r < 128; r += 64) {
      const uint4* g = (const uint4*)(P.hb + ((size_t)(b * N + n0 + r)) * F) + q * 4;
      uint4* lp = (uint4*)(sm->Bs + r * LK) + q * 4;
      lp[0] = g[0]; lp[1] = g[1]; lp[2] = g[2]; lp[3] = g[3];
    }
  }
  __syncthreads();
  int arow = lane & 15, koff = (lane >> 4) * 8;
  f32x4 acc[4][2] = {};
#pragma unroll
  for (int ks = 0; ks < 4; ks++) {
    short8 a[4], bb[2];
#pragma unroll
    for (int rt = 0; rt < 4; rt++)
      a[rt] = *(const short8*)(sm->As + (rt * 16 + arow) * LK + ks * 32 + koff);
#pragma unroll
    for (int cj = 0; cj < 2; cj++)
      bb[cj] = *(const short8*)(sm->Bs + ((2 * w + cj) * 16 + arow) * LK +
                                ks * 32 + koff);
#pragma unroll
    for (int rt = 0; rt < 4; rt++)
#pragma unroll
      for (int cj = 0; cj < 2; cj++)
        acc[rt][cj] = mfma16(a[rt], bb[cj], acc[rt][cj]);
  }
  short* outp = P.hhT + (size_t)bh * F * N;
  int crow0 = (lane >> 4) * 4;
#pragma unroll
  for (int rt = 0; rt < 4; rt++)
#pragma unroll
    for (int cj = 0; cj < 2; cj++) {
      int fo = ft * 64 + rt * 16 + crow0;
      int n = n0 + (2 * w + cj) * 16 + arow;
#pragma unroll
      for (int r = 0; r < 4; r++)
        outp[(size_t)(fo + r) * N + n] = f2bf(acc[rt][cj][r]);
    }
  const float* ah = ah_base + (size_t)hd * 2 * F;
  float pa1[2] = {0.f, 0.f}, pa2[2] = {0.f, 0.f};
#pragma unroll
  for (int rt = 0; rt < 4; rt++) {
    int fo = ft * 64 + rt * 16 + crow0;
#pragma unroll
    for (int r = 0; r < 4; r++) {
      float a1v = ah[fo + r], a2v = ah[F + fo + r];
      pa1[0] = fmaf(a1v, acc[rt][0][r], pa1[0]);
      pa1[1] = fmaf(a1v, acc[rt][1][r], pa1[1]);
      pa2[0] = fmaf(a2v, acc[rt][0][r], pa2[0]);
      pa2[1] = fmaf(a2v, acc[rt][1][r], pa2[1]);
    }
  }
#pragma unroll
  for (int cj = 0; cj < 2; cj++) {
    float v1 = pa1[cj], v2 = pa2[cj];
    v1 += __shfl_xor(v1, 16); v1 += __shfl_xor(v1, 32);
    v2 += __shfl_xor(v2, 16); v2 += __shfl_xor(v2, 32);
    if (lane < 16) {
      int n = n0 + (2 * w + cj) * 16 + lane;
      atomicAdd(&s1[(size_t)bh * N + n], v1);
      atomicAdd(&s2[(size_t)bh * N + n], v2);
    }
  }
}

// ====== attention, 8 heads, single-pass softmax, ELU -> multi (bf16) ======
// 512 units: nt(8) x hd(8) x b(8)
__device__ __forceinline__ void st_attn_heads(
    const KParams& P, const float* s1g, const float* s2g, int bid, int tid,
    char* smraw) {
  SM_AH* sm = (SM_AH*)smraw;
  int nt = bid & 7, hd = (bid >> 3) & 7, b = bid >> 6;
  int n0 = nt * 64, bh = b * H + hd;
  constexpr int LVK = 136;
  int lane = tid & 63, w = tid >> 6;
  sm->s2all[tid] = s2g[(size_t)bh * N + tid];
  sm->s2all[tid + 256] = s2g[(size_t)bh * N + tid + 256];
  if (tid < 64) sm->s1r[tid] = s1g[(size_t)bh * N + n0 + tid];
  __syncthreads();
  {  // prepass: per-row masked max of s2 (LeakyReLU monotone)
    const unsigned long long* mq = P.amask + ((size_t)(b * N + n0 + lane)) * 8;
    float mx = FLOW;
#pragma unroll
    for (int j = 0; j < 2; j++) {
      unsigned long long mb = mq[w * 2 + j];
      int base = w * 128 + j * 64;
      unsigned lo = (unsigned)mb, hi = (unsigned)(mb >> 32);
#pragma unroll
      for (int k = 0; k < 32; k++) {
        mx = ((lo >> k) & 1u) ? fmaxf(mx, sm->s2all[base + k]) : mx;
        mx = ((hi >> k) & 1u) ? fmaxf(mx, sm->s2all[base + 32 + k]) : mx;
      }
    }
    sm->red[lane][w] = mx;
  }
  __syncthreads();
  if (tid < 64) {
    float m2 = fmaxf(fmaxf(sm->red[tid][0], sm->red[tid][1]),
                     fmaxf(sm->red[tid][2], sm->red[tid][3]));
    float xm = sm->s1r[tid] + m2;
    sm->mrow[tid] = xm > 0.f ? xm : ALPHA_LR * xm;
  }
  float lp = 0.f;
  int arow = lane & 15, koff = (lane >> 4) * 8;
  f32x4 acc[4][2] = {};
  const short* Vg = P.hhT + (size_t)bh * F * N;
  const unsigned long long* mp = P.amask + ((size_t)(b * N + n0 + lane)) * 8;
  for (int mc = 0; mc < 4; mc++) {
    int m0 = mc * 128;
    __syncthreads();
    {  // stage V^T chunk: 128 f x 128 m
      int fr = tid >> 1, hf = tid & 1;
      const uint4* g4 = (const uint4*)(Vg + (size_t)fr * N + m0 + hf * 64);
      uint4* l4 = (uint4*)(sm->Vs + fr * LVK + hf * 64);
#pragma unroll
      for (int k = 0; k < 8; k++) l4[k] = g4[k];
    }
    {  // P: row = lane, k-range = w*32..+32, A-fragment order
      float s1v = sm->s1r[lane], mr = sm->mrow[lane];
      unsigned bits = (unsigned)(mp[mc * 2 + (w >> 1)] >> ((w & 1) * 32));
      short* pbase = sm->Pf + (((lane >> 4) * 4 + w) * 64) * 8;
#pragma unroll
      for (int q = 0; q < 4; q++) {
        short8 pk;
#pragma unroll
        for (int j = 0; j < 8; j++) {
          float xv = s1v + sm->s2all[m0 + w * 32 + q * 8 + j];
          xv = xv > 0.f ? xv : ALPHA_LR * xv;
          float p = __expf(xv - mr);
          p = ((bits >> (q * 8 + j)) & 1u) ? p : 0.f;
          lp += p;
          pk[j] = f2bf(p);
        }
        *(short8*)(pbase + ((q << 4) | (lane & 15)) * 8) = pk;
      }
    }
    __syncthreads();
#pragma unroll
    for (int ks = 0; ks < 4; ks++) {
      short8 a[4];
#pragma unroll
      for (int rt = 0; rt < 4; rt++)
        a[rt] = *(const short8*)(sm->Pf + ((rt * 4 + ks) * 64 + lane) * 8);
#pragma unroll
      for (int cj = 0; cj < 2; cj++) {
        short8 bb = *(const short8*)(sm->Vs + ((w * 2 + cj) * 16 + arow) * LVK +
                                     ks * 32 + koff);
#pragma unroll
        for (int rt = 0; rt < 4; rt++)
          acc[rt][cj] = mfma16(a[rt], bb, acc[rt][cj]);
      }
    }
  }
  __syncthreads();
  sm->red[lane][w] = lp;
  __syncthreads();
  if (tid < 64)
    sm->linv[tid] = 1.f / (sm->red[tid][0] + sm->red[tid][1] +
                           sm->red[tid][2] + sm->red[tid][3]);
  __syncthreads();
  int crow0 = (lane >> 4) * 4;
#pragma unroll
  for (int rt = 0; rt < 4; rt++)
#pragma unroll
    for (int cj = 0; cj < 2; cj++) {
      int fcol = (w * 2 + cj) * 16 + arow;
#pragma unroll
      for (int rr = 0; rr < 4; rr++) {
        int nrow = rt * 16 + crow0 + rr;
        float v = acc[rt][cj][rr] * sm->linv[nrow];
        v = v > 0.f ? v : __expf(v) - 1.f;  // ELU
        P.multi[((size_t)(b * N + n0 + nrow)) * (H * F) + hd * F + fcol] =
            f2bf(v);
      }
    }
}

// ====== out projection: hsT[b][f_out][n] = WoT.multi^T, 32x32 tiles ========
// 512 units: ft(4) x nt(16) x b(8)
__device__ __forceinline__ void st_proj_out(
    const KParams& P, const short* WoT, const float* ao, float* s1, float* s2,
    int bid, int tid, char* smraw) {
  SM_PO* sm = (SM_PO*)smraw;
  int ft = bid & 3, nt = (bid >> 2) & 15, b = bid >> 6;
  int f0 = ft * 32, nb = nt * 32;
  constexpr int LK = 136;
  int lane = tid & 63, w = tid >> 6;
  int rt = w & 1, ct = w >> 1;
  int arow = lane & 15, koff = (lane >> 4) * 8;
  const int KT = H * F;  // 1024
  f32x4 acc = {};
  for (int k0 = 0; k0 < KT; k0 += 128) {
    __syncthreads();
    {
      int r = tid >> 3, e = tid & 7;
      const uint4* gp = (const uint4*)(WoT + (size_t)(f0 + r) * KT + k0) + e * 2;
      uint4* lp = (uint4*)(sm->As + r * LK) + e * 2;
      lp[0] = gp[0]; lp[1] = gp[1];
    }
    {
      int r = tid >> 3, e = tid & 7;
      const uint4* gp =
          (const uint4*)(P.multi + (size_t)(b * N + nb + r) * KT + k0) + e * 2;
      uint4* lp = (uint4*)(sm->Bs + r * LK) + e * 2;
      lp[0] = gp[0]; lp[1] = gp[1];
    }
    __syncthreads();
#pragma unroll
    for (int ks = 0; ks < 4; ks++) {
      short8 a = *(const short8*)(sm->As + (rt * 16 + arow) * LK + ks * 32 + koff);
      short8 bb = *(const short8*)(sm->Bs + (ct * 16 + arow) * LK + ks * 32 + koff);
      acc = mfma16(a, bb, acc);
    }
  }
  int crow0 = (lane >> 4) * 4;
  short* op = P.hsT + (size_t)b * F * N;
#pragma unroll
  for (int r = 0; r < 4; r++)
    op[(size_t)(f0 + rt * 16 + crow0 + r) * N + nb + ct * 16 + arow] =
        f2bf(acc[r]);
  float pa1 = 0.f, pa2 = 0.f;
  {
    int fo = f0 + rt * 16 + crow0;
#pragma unroll
    for (int r = 0; r < 4; r++) {
      pa1 = fmaf(ao[fo + r], acc[r], pa1);
      pa2 = fmaf(ao[F + fo + r], acc[r], pa2);
    }
  }
  pa1 += __shfl_xor(pa1, 16); pa1 += __shfl_xor(pa1, 32);
  pa2 += __shfl_xor(pa2, 16); pa2 += __shfl_xor(pa2, 32);
  if (lane < 16) {
    int n = nb + ct * 16 + lane;
    atomicAdd(&s1[(size_t)b * N + n], pa1);
    atomicAdd(&s2[(size_t)b * N + n], pa2);
  }
}

// ====== single-head attention + residual + LayerNorm (+relu / d_out) ======
// 256 units: nt(32) x b(8)
__device__ __forceinline__ void st_attn_single(
    const KParams& P, const float* s1g, const float* s2g, const float* lng,
    const float* lnb, int last, int bid, int tid, char* smraw) {
  SM_AS* sm = (SM_AS*)smraw;
  int nt = bid & 31, b = bid >> 5;
  int n0 = nt * 16;
  constexpr int LVK = 136;
  int lane = tid & 63, w = tid >> 6;
  sm->s2all[tid] = s2g[(size_t)b * N + tid];
  sm->s2all[tid + 256] = s2g[(size_t)b * N + tid + 256];
  if (tid < 16) sm->s1r[tid] = s1g[(size_t)b * N + n0 + tid];
  __syncthreads();
  {  // prepass masked max
    int r = tid & 15, seg = tid >> 4;
    unsigned long long mb =
        P.amask[((size_t)(b * N + n0 + r)) * 8 + (seg >> 1)];
    unsigned bits = (unsigned)(mb >> ((seg & 1) * 32));
    float mx = FLOW;
#pragma unroll
    for (int k = 0; k < 32; k++)
      mx = ((bits >> k) & 1u) ? fmaxf(mx, sm->s2all[seg * 32 + k]) : mx;
    sm->redS[r][seg] = mx;
  }
  __syncthreads();
  if (tid < 16) {
    float m2 = FLOW;
#pragma unroll
    for (int k = 0; k < 16; k++) m2 = fmaxf(m2, sm->redS[tid][k]);
    float xm = sm->s1r[tid] + m2;
    sm->mrow[tid] = xm > 0.f ? xm : ALPHA_LR * xm;
  }
  float lp = 0.f;
  int arow = lane & 15, koff = (lane >> 4) * 8;
  int pr = tid & 15, pq = (tid >> 4) & 3;
  f32x4 acc[2] = {};
  const short* Vg = P.hsT + (size_t)b * F * N;
  const unsigned long long* mp = P.amask + ((size_t)(b * N + n0 + pr)) * 8;
  for (int mc = 0; mc < 4; mc++) {
    int m0 = mc * 128;
    __syncthreads();
    {
      int fr = tid >> 1, hf = tid & 1;
      const uint4* g4 = (const uint4*)(Vg + (size_t)fr * N + m0 + hf * 64);
      uint4* l4 = (uint4*)(sm->Vs + fr * LVK + hf * 64);
#pragma unroll
      for (int k = 0; k < 8; k++) l4[k] = g4[k];
    }
    {
      float s1v = sm->s1r[pr], mr = sm->mrow[pr];
      unsigned bits = (unsigned)(mp[mc * 2 + (w >> 1)] >> ((w & 1) * 32));
      short8 pk;
#pragma unroll
      for (int j = 0; j < 8; j++) {
        float xv = s1v + sm->s2all[m0 + w * 32 + pq * 8 + j];
        xv = xv > 0.f ? xv : ALPHA_LR * xv;
        float p = __expf(xv - mr);
        p = ((bits >> (pq * 8 + j)) & 1u) ? p : 0.f;
        lp += p;
        pk[j] = f2bf(p);
      }
      *(short8*)(sm->Pf + (w * 64 + ((pq << 4) | pr)) * 8) = pk;
    }
    __syncthreads();
#pragma unroll
    for (int ks = 0; ks < 4; ks++) {
      short8 a = *(const short8*)(sm->Pf + (ks * 64 + lane) * 8);
#pragma unroll
      for (int cj = 0; cj < 2; cj++) {
        short8 bb = *(const short8*)(sm->Vs + ((w * 2 + cj) * 16 + arow) * LVK +
                                     ks * 32 + koff);
        acc[cj] = mfma16(a, bb, acc[cj]);
      }
    }
  }
  __syncthreads();
  sm->redS[pr][tid >> 4] = lp;
  __syncthreads();
  if (tid < 16) {
    float l = 0.f;
#pragma unroll
    for (int k = 0; k < 16; k++) l += sm->redS[tid][k];
    sm->linv[tid] = 1.f / l;
  }
  __syncthreads();
  int crow0 = (lane >> 4) * 4;
#pragma unroll
  for (int cj = 0; cj < 2; cj++) {
    int fcol = (w * 2 + cj) * 16 + arow;
#pragma unroll
    for (int rr = 0; rr < 4; rr++) {
      int row = crow0 + rr;
      sm->Ot[row][fcol] = acc[cj][rr] * sm->linv[row];
    }
  }
  __syncthreads();
  int r2 = tid >> 4, f8 = (tid & 15) * 8;
  size_t gbase = ((size_t)(b * N + n0 + r2)) * F + f8;
  float v[8];
  float s = 0.f, sq = 0.f;
#pragma unroll
  for (int j = 0; j < 8; j++) {
    float t = sm->Ot[r2][f8 + j] + P.h[gbase + j];
    v[j] = t;
    s += t;
    sq = fmaf(t, t, sq);
  }
  sm->redS[r2][tid & 15] = s;
  sm->redQ[r2][tid & 15] = sq;
  __syncthreads();
  if (tid < 16) {
    float ss = 0.f, qq = 0.f;
#pragma unroll
    for (int k = 0; k < 16; k++) { ss += sm->redS[tid][k]; qq += sm->redQ[tid][k]; }
    float mu = ss * (1.f / F);
    sm->muA[tid] = mu;
    sm->rsA[tid] = rsqrtf(qq * (1.f / F) - mu * mu + EPS_LN);
  }
  __syncthreads();
  float mu = sm->muA[r2], rs = sm->rsA[r2];
#pragma unroll
  for (int j = 0; j < 8; j++) {
    float y = (v[j] - mu) * rs * lng[f8 + j] + lnb[f8 + j];
    if (last) {
      P.dout[gbase + j] = y;
    } else {
      y = fmaxf(y, 0.f);
      P.h[gbase + j] = y;
      P.hb[gbase + j] = f2bf(y);
    }
  }
}

// ============================ cooperative mega kernel =====================
__global__ __launch_bounds__(256, 2) void k_mega(KParams P) {
  cg::grid_group grid = cg::this_grid();
  __shared__ alignas(16) char smem[sizeof(SM_AH)];
  int bid = blockIdx.x, tid = threadIdx.x;

  st_setup(P, bid, tid, smem);
  __threadfence(); grid.sync();

  for (int l = 0; l < 2; l++) {
    const short* WTh_l = P.WTh + (size_t)l * H * F * F;
    const float* ah_l = P.a_heads + (size_t)l * H * 2 * F;
    const short* WoT_l = P.WoT + (size_t)l * H * F * F;
    const float* ao_l = P.a_out + (size_t)l * 2 * F;
    float* s1h = P.sA + (size_t)l * 73728;
    float* s2h = s1h + 32768;
    float* s1o = s2h + 32768;
    float* s2o = s1o + 4096;

    st_proj_heads(P, WTh_l, ah_l, s1h, s2h, bid, tid, smem);
    __threadfence(); grid.sync();
    st_attn_heads(P, s1h, s2h, bid, tid, smem);
    __threadfence(); grid.sync();
    st_proj_out(P, WoT_l, ao_l, s1o, s2o, bid, tid, smem);
    __threadfence(); grid.sync();
    if (bid < 256)
      st_attn_single(P, s1o, s2o, P.ln_g + (size_t)l * F,
                     P.ln_b + (size_t)l * F, l == 1, bid, tid, smem);
    if (l == 0) { __threadfence(); grid.sync(); }
  }
}

// ============================ fallback wrappers ===========================
__global__ __launch_bounds__(256) void g_setup(KParams P) {
  __shared__ alignas(16) char smem[sizeof(SM_SU)];
  st_setup(P, blockIdx.x, threadIdx.x, smem);
}
__global__ __launch_bounds__(256) void g_proj_heads(KParams P, int l) {
  __shared__ alignas(16) char smem[sizeof(SM_PH)];
  float* s1h = P.sA + (size_t)l * 73728;
  st_proj_heads(P, P.WTh + (size_t)l * H * F * F,
                P.a_heads + (size_t)l * H * 2 * F, s1h, s1h + 32768,
                blockIdx.x, threadIdx.x, smem);
}
__global__ __launch_bounds__(256) void g_attn_heads(KParams P, int l) {
  __shared__ alignas(16) char smem[sizeof(SM_AH)];
  float* s1h = P.sA + (size_t)l * 73728;
  st_attn_heads(P, s1h, s1h + 32768, blockIdx.x, threadIdx.x, smem);
}
__global__ __launch_bounds__(256) void g_proj_out(KParams P, int l) {
  __shared__ alignas(16) char smem[sizeof(SM_PO)];
  float* s1o = P.sA + (size_t)l * 73728 + 65536;
  st_proj_out(P, P.WoT + (size_t)l * H * F * F,
              P.a_out + (size_t)l * 2 * F, s1o, s1o + 4096, blockIdx.x,
              threadIdx.x, smem);
}
__global__ __launch_bounds__(256) void g_attn_single(KParams P, int l) {
  __shared__ alignas(16) char smem[sizeof(SM_AS)];
  float* s1o = P.sA + (size_t)l * 73728 + 65536;
  st_attn_single(P, s1o, s1o + 4096, P.ln_g + (size_t)l * F,
                 P.ln_b + (size_t)l * F, l == 1, blockIdx.x, threadIdx.x,
                 smem);
}

extern "C" void kernel_launch(void* const* d_in, const int* in_sizes, int n_in,
                              void* d_out, int out_size, void* d_ws,
                              size_t ws_size, hipStream_t stream) {
  char* p = (char*)d_ws;
  auto alloc = [&](size_t bytes) {
    char* r = p;
    p += (bytes + 255) & ~(size_t)255;
    return r;
  };
  KParams P;
  P.x = (const float*)d_in[0];
  P.adj = (const int*)d_in[1];
  P.Wp = (const float*)d_in[2];
  P.bp = (const float*)d_in[3];
  P.W_heads = (const float*)d_in[4];
  P.a_heads = (const float*)d_in[5];
  P.W_out = (const float*)d_in[6];
  P.a_out = (const float*)d_in[7];
  P.ln_g = (const float*)d_in[8];
  P.ln_b = (const float*)d_in[9];
  P.sA = (float*)alloc((size_t)2 * 73728 * 4);
  P.WTh = (short*)alloc((size_t)2 * H * F * F * 2);
  P.WoT = (short*)alloc((size_t)2 * H * F * F * 2);
  P.amask = (unsigned long long*)alloc((size_t)BN * 8 * 8);
  P.h = (float*)alloc((size_t)BN * F * 4);
  P.hb = (short*)alloc((size_t)BN * F * 2);
  P.hhT = (short*)alloc((size_t)B * H * F * N * 2);
  P.multi = (short*)alloc((size_t)BN * H * F * 2);
  P.hsT = (short*)alloc((size_t)B * F * N * 2);
  P.dout = (float*)d_out;

  // Occupancy-gated cooperative path: need 2 blocks/CU for 512 co-resident.
  int occ = 0;
  (void)hipOccupancyMaxActiveBlocksPerMultiprocessor(&occ, k_mega, 256, 0);
  if (occ >= 2) {
    void* kargs[] = {&P};
    hipError_t e = hipLaunchCooperativeKernel((void*)k_mega, dim3(512),
                                              dim3(256), kargs, 0, stream);
    if (e == hipSuccess) return;
    (void)hipGetLastError();  // clear sticky error, take fallback
  }
  // Fallback: proven multi-kernel pipeline (same stage code).
  g_setup<<<512, 256, 0, stream>>>(P);
  for (int l = 0; l < 2; l++) {
    g_proj_heads<<<512, 256, 0, stream>>>(P, l);
    g_attn_heads<<<512, 256, 0, stream>>>(P, l);
    g_proj_out<<<512, 256, 0, stream>>>(P, l);
    g_attn_single<<<256, 256, 0, stream>>>(P, l);
  }
}